// Round 1
// baseline (141.919 us; speedup 1.0000x reference)
//
#include <hip/hip_runtime.h>
#include <hip/hip_bf16.h>
#include <stdint.h>

typedef float f32x4 __attribute__((ext_vector_type(4)));
typedef short short8 __attribute__((ext_vector_type(8)));

#define D_MODEL 512
#define MAX_LEN 1024
#define M_TOTAL 65536

static __device__ __forceinline__ short f2bf(float f) {
  union { __hip_bfloat16 h; short s; } u;
  u.h = __float2bfloat16(f);
  return u.s;
}

// async global->LDS, 16B per lane. LDS dest must be wave-uniform base + lane*16.
static __device__ __forceinline__ void gload_lds16(const void* g, void* l) {
  __builtin_amdgcn_global_load_lds(
      (const __attribute__((address_space(1))) uint32_t*)(uintptr_t)g,
      (__attribute__((address_space(3))) uint32_t*)(uint32_t)(uintptr_t)l,
      16, 0, 0);
}

static __device__ __forceinline__ void mfma_bf16(f32x4& c, short8 a, short8 b) {
  asm("v_mfma_f32_16x16x32_bf16 %0, %1, %2, %0" : "+v"(c) : "v"(a), "v"(b));
}

// ---------------- prep: W [1024][512] f32 -> WtopT / WbotT [512][512] bf16 ([n][k]) ----
__global__ __launch_bounds__(256) void prep_w_kernel(const float* __restrict__ W,
                                                     short* __restrict__ WtT,
                                                     short* __restrict__ WbT) {
  __shared__ float tile[64][65];
  const int t = threadIdx.x;
  const int nt = blockIdx.x * 64;   // n tile in [0,512)
  const int kt = blockIdx.y * 64;   // k tile in [0,1024)
  const int c = t & 63;
  const int r0 = t >> 6;
#pragma unroll
  for (int r = r0; r < 64; r += 4)
    tile[r][c] = W[(size_t)(kt + r) * D_MODEL + nt + c];
  __syncthreads();
  short* dst = (kt < D_MODEL) ? WtT : WbT;
  const int kb = kt & (D_MODEL - 1);
#pragma unroll
  for (int n = r0; n < 64; n += 4)
    dst[(size_t)(nt + n) * D_MODEL + kb + c] = f2bf(tile[c][n]);
}

// ---------------- prep: encoding [1024][512] f32 -> bf16 (row-major) -------------------
__global__ __launch_bounds__(256) void prep_enc_kernel(const float* __restrict__ enc,
                                                       short* __restrict__ encb) {
  const int i = (blockIdx.x * 256 + threadIdx.x) * 4;
  float4 v = *reinterpret_cast<const float4*>(enc + i);
  short4 r = make_short4(f2bf(v.x), f2bf(v.y), f2bf(v.z), f2bf(v.w));
  *reinterpret_cast<short4*>(encb + i) = r;
}

// ---------------- GEMM1: encW[1024][512] = enc_bf16 @ WtopT^T (fp32 out) ---------------
// 128x128 tile, BK=32, 4 waves (2x2), 16x16x32 bf16 MFMA, 4x4 frags/wave.
__global__ __launch_bounds__(256) void gemm_encw_kernel(const short* __restrict__ A,
                                                        const short* __restrict__ BT,
                                                        float* __restrict__ C) {
  __shared__ short As[128 * 32];
  __shared__ short Bs[128 * 32];
  const int t = threadIdx.x;
  const int lane = t & 63;
  const int wave = t >> 6;
  const int wm = wave >> 1, wn = wave & 1;
  const int m0 = blockIdx.y * 128, n0 = blockIdx.x * 128;
  const int koff = (t & 3) * 8;
  const int rr = t >> 2;
  const int l15 = lane & 15, lk = (lane >> 4) * 8;
  f32x4 acc[4][4] = {};
  for (int kt = 0; kt < D_MODEL; kt += 32) {
    __syncthreads();
    gload_lds16(A + (size_t)(m0 + rr) * D_MODEL + kt + koff, (char*)As + t * 16);
    gload_lds16(A + (size_t)(m0 + 64 + rr) * D_MODEL + kt + koff, (char*)As + 4096 + t * 16);
    gload_lds16(BT + (size_t)(n0 + rr) * D_MODEL + kt + koff, (char*)Bs + t * 16);
    gload_lds16(BT + (size_t)(n0 + 64 + rr) * D_MODEL + kt + koff, (char*)Bs + 4096 + t * 16);
    __syncthreads();
    short8 af[4], bfr[4];
#pragma unroll
    for (int mi = 0; mi < 4; ++mi)
      af[mi] = *reinterpret_cast<const short8*>(&As[(wm * 64 + mi * 16 + l15) * 32 + lk]);
#pragma unroll
    for (int ni = 0; ni < 4; ++ni)
      bfr[ni] = *reinterpret_cast<const short8*>(&Bs[(wn * 64 + ni * 16 + l15) * 32 + lk]);
#pragma unroll
    for (int mi = 0; mi < 4; ++mi)
#pragma unroll
      for (int ni = 0; ni < 4; ++ni)
        mfma_bf16(acc[mi][ni], af[mi], bfr[ni]);
  }
#pragma unroll
  for (int mi = 0; mi < 4; ++mi)
#pragma unroll
    for (int r = 0; r < 4; ++r) {
      const int row = m0 + wm * 64 + mi * 16 + (lane >> 4) * 4 + r;
#pragma unroll
      for (int ni = 0; ni < 4; ++ni) {
        const int col = n0 + wn * 64 + ni * 16 + l15;
        C[(size_t)row * D_MODEL + col] = acc[mi][ni][r];
      }
    }
}

// ---------------- GEMM2: out = latent @ WbotT^T + encW[dfn] + encW[dfa] + b ------------
__global__ __launch_bounds__(256) void gemm_main_kernel(
    const float* __restrict__ latent,   // [65536][512] f32
    const short* __restrict__ BT,       // WbotT [512][512] bf16 ([n][k])
    const float* __restrict__ encW,     // [1024][512] f32
    const int* __restrict__ dfn,
    const int* __restrict__ dfa,
    const float* __restrict__ bias,     // [512]
    float* __restrict__ out) {          // [65536][512] f32
  __shared__ short As[128 * 32];
  __shared__ short Bs[128 * 32];
  const int t = threadIdx.x;
  const int lane = t & 63;
  const int wave = t >> 6;
  const int wm = wave >> 1, wn = wave & 1;
  const int n0 = blockIdx.x * 128;
  const int m0 = blockIdx.y * 128;
  const int koff = (t & 3) * 8;
  const int rr = t >> 2;
  const int l15 = lane & 15, lk = (lane >> 4) * 8;
  f32x4 acc[4][4] = {};

  for (int kt = 0; kt < D_MODEL; kt += 32) {
    __syncthreads();
    // B tile: bf16, linear -> global_load_lds
    gload_lds16(BT + (size_t)(n0 + rr) * D_MODEL + kt + koff, (char*)Bs + t * 16);
    gload_lds16(BT + (size_t)(n0 + 64 + rr) * D_MODEL + kt + koff, (char*)Bs + 4096 + t * 16);
    // A tile: fp32 -> bf16 reg-staged (conversion forces the register round-trip)
#pragma unroll
    for (int i = 0; i < 2; ++i) {
      const int m = rr + i * 64;
      const float* src = latent + (size_t)(m0 + m) * D_MODEL + kt + koff;
      float4 v0 = *reinterpret_cast<const float4*>(src);
      float4 v1 = *reinterpret_cast<const float4*>(src + 4);
      short8 h;
      h[0] = f2bf(v0.x); h[1] = f2bf(v0.y); h[2] = f2bf(v0.z); h[3] = f2bf(v0.w);
      h[4] = f2bf(v1.x); h[5] = f2bf(v1.y); h[6] = f2bf(v1.z); h[7] = f2bf(v1.w);
      *reinterpret_cast<short8*>(&As[m * 32 + koff]) = h;
    }
    __syncthreads();
    short8 af[4], bfr[4];
#pragma unroll
    for (int mi = 0; mi < 4; ++mi)
      af[mi] = *reinterpret_cast<const short8*>(&As[(wm * 64 + mi * 16 + l15) * 32 + lk]);
#pragma unroll
    for (int ni = 0; ni < 4; ++ni)
      bfr[ni] = *reinterpret_cast<const short8*>(&Bs[(wn * 64 + ni * 16 + l15) * 32 + lk]);
#pragma unroll
    for (int mi = 0; mi < 4; ++mi)
#pragma unroll
      for (int ni = 0; ni < 4; ++ni)
        mfma_bf16(acc[mi][ni], af[mi], bfr[ni]);
  }

  // epilogue: fused gather of encW rows (2 MB, L2-resident) + bias
#pragma unroll
  for (int mi = 0; mi < 4; ++mi) {
#pragma unroll
    for (int r = 0; r < 4; ++r) {
      const int row = m0 + wm * 64 + mi * 16 + (lane >> 4) * 4 + r;
      const int d1 = dfn[row];
      const int d2 = dfa[row];
      const float* e1 = encW + (size_t)d1 * D_MODEL;
      const float* e2 = encW + (size_t)d2 * D_MODEL;
      const size_t ro = (size_t)row * D_MODEL;
#pragma unroll
      for (int ni = 0; ni < 4; ++ni) {
        const int col = n0 + wn * 64 + ni * 16 + l15;
        out[ro + col] = acc[mi][ni][r] + e1[col] + e2[col] + bias[col];
      }
    }
  }
}

extern "C" void kernel_launch(void* const* d_in, const int* in_sizes, int n_in,
                              void* d_out, int out_size, void* d_ws, size_t ws_size,
                              hipStream_t stream) {
  const int* dfn = (const int*)d_in[0];
  const int* dfa = (const int*)d_in[1];
  const float* latent = (const float*)d_in[2];
  const float* enc = (const float*)d_in[3];
  const float* W = (const float*)d_in[4];
  const float* bias = (const float*)d_in[5];
  float* out = (float*)d_out;

  // workspace layout (4 MB total)
  char* ws = (char*)d_ws;
  short* WtT  = (short*)(ws);                       // 512KB  [512][512] bf16
  short* WbT  = (short*)(ws + 512 * 1024);          // 512KB  [512][512] bf16
  short* encb = (short*)(ws + 1024 * 1024);         // 1MB    [1024][512] bf16
  float* encW = (float*)(ws + 2 * 1024 * 1024);     // 2MB    [1024][512] f32

  hipLaunchKernelGGL(prep_w_kernel, dim3(8, 16), dim3(256), 0, stream, W, WtT, WbT);
  hipLaunchKernelGGL(prep_enc_kernel, dim3(512), dim3(256), 0, stream, enc, encb);
  hipLaunchKernelGGL(gemm_encw_kernel, dim3(4, 8), dim3(256), 0, stream, encb, WtT, encW);
  hipLaunchKernelGGL(gemm_main_kernel, dim3(4, 512), dim3(256), 0, stream,
                     latent, WbT, encW, dfn, dfa, bias, out);
}

// Round 2
// 133.249 us; speedup vs baseline: 1.0651x; 1.0651x over previous
//
#include <hip/hip_runtime.h>
#include <hip/hip_bf16.h>
#include <stdint.h>

typedef float f32x4 __attribute__((ext_vector_type(4)));
typedef short short8 __attribute__((ext_vector_type(8)));

#define D_MODEL 512
#define MAX_LEN 1024
#define M_TOTAL 65536

static __device__ __forceinline__ short f2bf(float f) {
  union { __hip_bfloat16 h; short s; } u;
  u.h = __float2bfloat16(f);
  return u.s;
}

// async global->LDS, 16B per lane. LDS dest must be wave-uniform base + lane*16.
static __device__ __forceinline__ void gload_lds16(const void* g, void* l) {
  __builtin_amdgcn_global_load_lds(
      (const __attribute__((address_space(1))) uint32_t*)(uintptr_t)g,
      (__attribute__((address_space(3))) uint32_t*)(uint32_t)(uintptr_t)l,
      16, 0, 0);
}

static __device__ __forceinline__ void mfma_bf16(f32x4& c, short8 a, short8 b) {
  asm("v_mfma_f32_16x16x32_bf16 %0, %1, %2, %0" : "+v"(c) : "v"(a), "v"(b));
}

// ---------------- prep: W [1024][512] f32 -> WtopT / WbotT [512][512] bf16 ([n][k]) ----
__global__ __launch_bounds__(256) void prep_w_kernel(const float* __restrict__ W,
                                                     short* __restrict__ WtT,
                                                     short* __restrict__ WbT) {
  __shared__ float tile[64][65];
  const int t = threadIdx.x;
  const int nt = blockIdx.x * 64;   // n tile in [0,512)
  const int kt = blockIdx.y * 64;   // k tile in [0,1024)
  const int c = t & 63;
  const int r0 = t >> 6;
#pragma unroll
  for (int r = r0; r < 64; r += 4)
    tile[r][c] = W[(size_t)(kt + r) * D_MODEL + nt + c];
  __syncthreads();
  short* dst = (kt < D_MODEL) ? WtT : WbT;
  const int kb = kt & (D_MODEL - 1);
#pragma unroll
  for (int n = r0; n < 64; n += 4)
    dst[(size_t)(nt + n) * D_MODEL + kb + c] = f2bf(tile[c][n]);
}

// ---------------- prep: encoding [1024][512] f32 -> bf16 (row-major) -------------------
__global__ __launch_bounds__(256) void prep_enc_kernel(const float* __restrict__ enc,
                                                       short* __restrict__ encb) {
  const int i = (blockIdx.x * 256 + threadIdx.x) * 4;
  float4 v = *reinterpret_cast<const float4*>(enc + i);
  short4 r = make_short4(f2bf(v.x), f2bf(v.y), f2bf(v.z), f2bf(v.w));
  *reinterpret_cast<short4*>(encb + i) = r;
}

// ---------------- GEMM1: encW[1024][512] = enc_bf16 @ WtopT^T (fp32 out) ---------------
// 128x128 tile, BK=32, 4 waves (2x2), 16x16x32 bf16 MFMA, 4x4 frags/wave. (small; as-is)
__global__ __launch_bounds__(256) void gemm_encw_kernel(const short* __restrict__ A,
                                                        const short* __restrict__ BT,
                                                        float* __restrict__ C) {
  __shared__ short As[128 * 32];
  __shared__ short Bs[128 * 32];
  const int t = threadIdx.x;
  const int lane = t & 63;
  const int wave = t >> 6;
  const int wm = wave >> 1, wn = wave & 1;
  const int m0 = blockIdx.y * 128, n0 = blockIdx.x * 128;
  const int koff = (t & 3) * 8;
  const int rr = t >> 2;
  const int l15 = lane & 15, lk = (lane >> 4) * 8;
  f32x4 acc[4][4] = {};
  for (int kt = 0; kt < D_MODEL; kt += 32) {
    __syncthreads();
    gload_lds16(A + (size_t)(m0 + rr) * D_MODEL + kt + koff, (char*)As + t * 16);
    gload_lds16(A + (size_t)(m0 + 64 + rr) * D_MODEL + kt + koff, (char*)As + 4096 + t * 16);
    gload_lds16(BT + (size_t)(n0 + rr) * D_MODEL + kt + koff, (char*)Bs + t * 16);
    gload_lds16(BT + (size_t)(n0 + 64 + rr) * D_MODEL + kt + koff, (char*)Bs + 4096 + t * 16);
    __syncthreads();
    short8 af[4], bfr[4];
#pragma unroll
    for (int mi = 0; mi < 4; ++mi)
      af[mi] = *reinterpret_cast<const short8*>(&As[(wm * 64 + mi * 16 + l15) * 32 + lk]);
#pragma unroll
    for (int ni = 0; ni < 4; ++ni)
      bfr[ni] = *reinterpret_cast<const short8*>(&Bs[(wn * 64 + ni * 16 + l15) * 32 + lk]);
#pragma unroll
    for (int mi = 0; mi < 4; ++mi)
#pragma unroll
      for (int ni = 0; ni < 4; ++ni)
        mfma_bf16(acc[mi][ni], af[mi], bfr[ni]);
  }
#pragma unroll
  for (int mi = 0; mi < 4; ++mi)
#pragma unroll
    for (int r = 0; r < 4; ++r) {
      const int row = m0 + wm * 64 + mi * 16 + (lane >> 4) * 4 + r;
#pragma unroll
      for (int ni = 0; ni < 4; ++ni) {
        const int col = n0 + wn * 64 + ni * 16 + l15;
        C[(size_t)row * D_MODEL + col] = acc[mi][ni][r];
      }
    }
}

// ---------------- GEMM2: out = latent @ WbotT^T + encW[dfn] + encW[dfa] + b ------------
// BM=128, BN=128, BK=64; T2 XOR-swizzled LDS (slot ^= row&7); XCD-chunked block map.
__global__ __launch_bounds__(256) void gemm_main_kernel(
    const float* __restrict__ latent,   // [65536][512] f32
    const short* __restrict__ BT,       // WbotT [512][512] bf16 ([n][k])
    const float* __restrict__ encW,     // [1024][512] f32
    const int* __restrict__ dfn,
    const int* __restrict__ dfa,
    const float* __restrict__ bias,     // [512]
    float* __restrict__ out) {          // [65536][512] f32
  __shared__ short As[128 * 64];  // 16 KB, row-major [128][64], XOR-swizzled slots
  __shared__ short Bs[128 * 64];  // 16 KB
  const int t = threadIdx.x;
  const int lane = t & 63;
  const int wave = t >> 6;
  const int wm = wave >> 1, wn = wave & 1;

  // XCD-chunked mapping: xcd = bid&7 owns m-panels [xcd*64, xcd*64+64);
  // the 4 n-blocks of each m-panel are consecutive slots -> same-XCD L2 reuse of A.
  const int bid = blockIdx.x;
  const int slot = bid >> 3;
  const int mblk = (bid & 7) * 64 + (slot >> 2);
  const int nblk = slot & 3;
  const int m0 = mblk * 128, n0 = nblk * 128;

  // B staging: chunk c covers rows c*32 + (t>>3); 16B slot sb = t&7 (LDS linear).
  const int rbb = t >> 3;
  const int sb = t & 7;
  // A staging: thread owns row ra = t>>1, cols [ha*32, ha*32+32).
  const int ra = t >> 1;
  const int ha = t & 1;

  const int l15 = lane & 15;
  const int lsl = lane >> 4;   // k sub-slot 0..3

  f32x4 acc[4][4] = {};

  for (int kt = 0; kt < D_MODEL; kt += 64) {
    __syncthreads();
    // ---- B tile via global_load_lds, source pre-swizzled so LDS[r][s] = global[r][s^(r&7)]
#pragma unroll
    for (int c = 0; c < 4; ++c) {
      const int r = c * 32 + rbb;
      const int sg = sb ^ (r & 7);
      gload_lds16(BT + (size_t)(n0 + r) * D_MODEL + kt + sg * 8,
                  (char*)Bs + c * 4096 + t * 16);
    }
    // ---- A tile: fp32 global -> regs -> cvt -> swizzled ds_write
    const float4* asrc =
        reinterpret_cast<const float4*>(latent + (size_t)(m0 + ra) * D_MODEL + kt + ha * 32);
    float4 av[8];
#pragma unroll
    for (int j = 0; j < 8; ++j) av[j] = asrc[j];
#pragma unroll
    for (int j = 0; j < 4; ++j) {
      short8 h8;
      h8[0] = f2bf(av[2 * j].x); h8[1] = f2bf(av[2 * j].y);
      h8[2] = f2bf(av[2 * j].z); h8[3] = f2bf(av[2 * j].w);
      h8[4] = f2bf(av[2 * j + 1].x); h8[5] = f2bf(av[2 * j + 1].y);
      h8[6] = f2bf(av[2 * j + 1].z); h8[7] = f2bf(av[2 * j + 1].w);
      const int sw = (ha * 4 + j) ^ (ra & 7);
      *reinterpret_cast<short8*>((char*)As + ra * 128 + sw * 16) = h8;
    }
    __syncthreads();
    // ---- fragments + MFMA, per 32-wide k-slice (kk)
#pragma unroll
    for (int kk = 0; kk < 2; ++kk) {
      short8 af[4], bfr[4];
#pragma unroll
      for (int mi = 0; mi < 4; ++mi) {
        const int r = wm * 64 + mi * 16 + l15;
        const int s = (kk * 4 + lsl) ^ (r & 7);
        af[mi] = *reinterpret_cast<const short8*>((char*)As + r * 128 + s * 16);
      }
#pragma unroll
      for (int ni = 0; ni < 4; ++ni) {
        const int r = wn * 64 + ni * 16 + l15;
        const int s = (kk * 4 + lsl) ^ (r & 7);
        bfr[ni] = *reinterpret_cast<const short8*>((char*)Bs + r * 128 + s * 16);
      }
#pragma unroll
      for (int mi = 0; mi < 4; ++mi)
#pragma unroll
        for (int ni = 0; ni < 4; ++ni)
          mfma_bf16(acc[mi][ni], af[mi], bfr[ni]);
    }
  }

  // epilogue: fused gather of encW rows (2 MB, L2-resident) + bias
#pragma unroll
  for (int mi = 0; mi < 4; ++mi) {
#pragma unroll
    for (int r = 0; r < 4; ++r) {
      const int row = m0 + wm * 64 + mi * 16 + (lane >> 4) * 4 + r;
      const int d1 = dfn[row];
      const int d2 = dfa[row];
      const float* e1 = encW + (size_t)d1 * D_MODEL;
      const float* e2 = encW + (size_t)d2 * D_MODEL;
      const size_t ro = (size_t)row * D_MODEL;
#pragma unroll
      for (int ni = 0; ni < 4; ++ni) {
        const int col = n0 + wn * 64 + ni * 16 + l15;
        out[ro + col] = acc[mi][ni][r] + e1[col] + e2[col] + bias[col];
      }
    }
  }
}

extern "C" void kernel_launch(void* const* d_in, const int* in_sizes, int n_in,
                              void* d_out, int out_size, void* d_ws, size_t ws_size,
                              hipStream_t stream) {
  const int* dfn = (const int*)d_in[0];
  const int* dfa = (const int*)d_in[1];
  const float* latent = (const float*)d_in[2];
  const float* enc = (const float*)d_in[3];
  const float* W = (const float*)d_in[4];
  const float* bias = (const float*)d_in[5];
  float* out = (float*)d_out;

  // workspace layout (4 MB total)
  char* ws = (char*)d_ws;
  short* WtT  = (short*)(ws);                       // 512KB  [512][512] bf16
  short* WbT  = (short*)(ws + 512 * 1024);          // 512KB  [512][512] bf16
  short* encb = (short*)(ws + 1024 * 1024);         // 1MB    [1024][512] bf16
  float* encW = (float*)(ws + 2 * 1024 * 1024);     // 2MB    [1024][512] f32

  hipLaunchKernelGGL(prep_w_kernel, dim3(8, 16), dim3(256), 0, stream, W, WtT, WbT);
  hipLaunchKernelGGL(prep_enc_kernel, dim3(512), dim3(256), 0, stream, enc, encb);
  hipLaunchKernelGGL(gemm_encw_kernel, dim3(4, 8), dim3(256), 0, stream, encb, WtT, encW);
  hipLaunchKernelGGL(gemm_main_kernel, dim3(2048), dim3(256), 0, stream,
                     latent, WbT, encW, dfn, dfa, bias, out);
}